// Round 1
// baseline (269.244 us; speedup 1.0000x reference)
//
#include <hip/hip_runtime.h>
#include <hip/hip_bf16.h>

typedef unsigned short u16;
typedef __attribute__((ext_vector_type(4))) float f32x4;
typedef __bf16 bf16x8 __attribute__((ext_vector_type(8)));

#define AS1 __attribute__((address_space(1)))
#define AS3 __attribute__((address_space(3)))

__device__ __forceinline__ void gload_lds16(const void* g, void* l) {
    __builtin_amdgcn_global_load_lds((const AS1 void*)g, (AS3 void*)l, 16, 0, 0);
}

// ---------------- transpose [B, IN, T] f32 -> [T, B, IN] bf16 ----------------
__global__ void transpose_x(const float* __restrict__ X, u16* __restrict__ Xb,
                            int B, int IN, int T) {
    __shared__ float tile[32][33];
    const int t0 = blockIdx.x * 32, i0 = blockIdx.y * 32, b = blockIdx.z;
    const int tx = threadIdx.x & 31, ty = threadIdx.x >> 5;
    const float* src = X + (size_t)b * IN * T;
#pragma unroll
    for (int r = 0; r < 4; ++r) {
        int i = ty + r * 8;
        tile[i][tx] = src[(size_t)(i0 + i) * T + t0 + tx];
    }
    __syncthreads();
#pragma unroll
    for (int r = 0; r < 4; ++r) {
        int tl = ty + r * 8;
        float v = tile[tx][tl];  // [i_loc=tx][t_loc=tl]
        Xb[(size_t)(t0 + tl) * ((size_t)B * IN) + (size_t)b * IN + i0 + tx] =
            (u16)(__float_as_uint(v) >> 16);   // 0.0/1.0 exact
    }
}

// ---------------- quantize: round(w/2)*2 (half-to-even), to bf16 -------------
__global__ void quant_w(const float* __restrict__ W, u16* __restrict__ Wq, int n) {
    int i = blockIdx.x * 256 + threadIdx.x;
    if (i < n) {
        float q = rintf(W[i] * 0.5f) * 2.0f;   // small even integer: bf16-exact
        Wq[i] = (u16)(__float_as_uint(q) >> 16);
    }
}

// ---------------- GEMM: C[M,N] f32 = A[M,K]bf16 * Bt[N,K]bf16 ----------------
// 128x128 tile, BK=64, 4 waves (2x2 of 64x64), 16x16x32 bf16 MFMA
__global__ __launch_bounds__(256, 2) void gemm_bt(
        const u16* __restrict__ A, const u16* __restrict__ Bt,
        float* __restrict__ C, int M, int N, int K) {
    __shared__ __align__(16) u16 lA[128 * 64];
    __shared__ __align__(16) u16 lB[128 * 64];
    const int tid  = threadIdx.x;
    const int lane = tid & 63;
    const int wave = tid >> 6;
    const int wm = wave >> 1, wn = wave & 1;
    const int m0 = blockIdx.y * 128;
    const int n0 = blockIdx.x * 128;
    const int l15 = lane & 15;
    const int l4  = lane >> 4;

    f32x4 acc[4][4] = {};

    const int flatT = tid * 8;  // 8 bf16 = 16B per lane per issue

    for (int k0 = 0; k0 < K; k0 += 64) {
        __syncthreads();
#pragma unroll
        for (int q = 0; q < 4; ++q) {
            int fl = q * 2048 + flatT;
            int r = fl >> 6, c = fl & 63;
            gload_lds16(A + (size_t)(m0 + r) * K + k0 + c, &lA[fl]);
        }
#pragma unroll
        for (int q = 0; q < 4; ++q) {
            int fl = q * 2048 + flatT;
            int r = fl >> 6, c = fl & 63;
            gload_lds16(Bt + (size_t)(n0 + r) * K + k0 + c, &lB[fl]);
        }
        __syncthreads();
#pragma unroll
        for (int kk = 0; kk < 2; ++kk) {
            bf16x8 af[4], bf[4];
#pragma unroll
            for (int mf = 0; mf < 4; ++mf)
                af[mf] = *(const bf16x8*)&lA[(wm * 64 + mf * 16 + l15) * 64 + kk * 32 + l4 * 8];
#pragma unroll
            for (int nf = 0; nf < 4; ++nf)
                bf[nf] = *(const bf16x8*)&lB[(wn * 64 + nf * 16 + l15) * 64 + kk * 32 + l4 * 8];
#pragma unroll
            for (int mf = 0; mf < 4; ++mf)
#pragma unroll
                for (int nf = 0; nf < 4; ++nf)
                    acc[mf][nf] = __builtin_amdgcn_mfma_f32_16x16x32_bf16(
                        af[mf], bf[nf], acc[mf][nf], 0, 0, 0);
        }
    }
#pragma unroll
    for (int mf = 0; mf < 4; ++mf)
#pragma unroll
        for (int nf = 0; nf < 4; ++nf) {
            int col = n0 + wn * 64 + nf * 16 + l15;
#pragma unroll
            for (int j = 0; j < 4; ++j) {
                int row = m0 + wm * 64 + mf * 16 + l4 * 4 + j;
                C[(size_t)row * N + col] = acc[mf][nf][j];
            }
        }
}

// ---------------- Loihi neuron scan, layer 1: H f32 -> pre-shifted bf16 spikes
__global__ void scan1(const float* __restrict__ H, u16* __restrict__ S, int BH, int T) {
    int idx = blockIdx.x * 256 + threadIdx.x;
    S[idx] = 0;                       // t=0 row (delay shift)
    float I = 0.f, V = 0.f;
    const float* p = H + idx;
    u16* q = S + idx;
    for (int t = 0; t < T; t += 4) {
        float h[4];
#pragma unroll
        for (int u = 0; u < 4; ++u) h[u] = p[(size_t)(t + u) * BH];
#pragma unroll
        for (int u = 0; u < 4; ++u) {
            I = floorf(I * 0.75f) + 64.f * h[u];
            V = floorf(V * 0.96875f) + I;
            float s = (V >= 5120.f) ? 1.f : 0.f;
            V *= (1.f - s);
            int tt = t + u + 1;
            if (tt < T) q[(size_t)tt * BH] = (s > 0.f) ? (u16)0x3F80 : (u16)0;
        }
    }
}

// ---------------- Loihi neuron scan, layer 2: O f32 -> pre-shifted f32 spikes
__global__ void scan2(const float* __restrict__ O, float* __restrict__ S, int BO, int T) {
    int idx = blockIdx.x * 256 + threadIdx.x;
    S[idx] = 0.f;
    float I = 0.f, V = 0.f;
    const float* p = O + idx;
    float* q = S + idx;
    for (int t = 0; t < T; t += 8) {
        float h[8];
#pragma unroll
        for (int u = 0; u < 8; ++u) h[u] = p[(size_t)(t + u) * BO];
#pragma unroll
        for (int u = 0; u < 8; ++u) {
            I = floorf(I * 0.75f) + 64.f * h[u];
            V = floorf(V * 0.96875f) + I;
            float s = (V >= 5120.f) ? 1.f : 0.f;
            V *= (1.f - s);
            int tt = t + u + 1;
            if (tt < T) q[(size_t)tt * BO] = s;
        }
    }
}

// ---------------- transpose [T, B, OUT] -> out [B, OUT, T] -------------------
__global__ void transpose_out(const float* __restrict__ S, float* __restrict__ out,
                              int B, int OUT, int T) {
    __shared__ float tile[32][33];
    const int t0 = blockIdx.x * 32, o0 = blockIdx.y * 32, b = blockIdx.z;
    const int tx = threadIdx.x & 31, ty = threadIdx.x >> 5;
#pragma unroll
    for (int r = 0; r < 4; ++r) {
        int t = ty + r * 8;
        tile[t][tx] = S[(size_t)(t0 + t) * B * OUT + (size_t)b * OUT + o0 + tx];
    }
    __syncthreads();
#pragma unroll
    for (int r = 0; r < 4; ++r) {
        int o = ty + r * 8;
        out[(size_t)b * OUT * T + (size_t)(o0 + o) * T + t0 + tx] = tile[tx][o];
    }
}

extern "C" void kernel_launch(void* const* d_in, const int* in_sizes, int n_in,
                              void* d_out, int out_size, void* d_ws, size_t ws_size,
                              hipStream_t stream) {
    const int B = 32, IN = 1024, HID = 2048, OUT = 512, T = 256;
    const float* spikes = (const float*)d_in[0];
    const float* W1 = (const float*)d_in[1];
    const float* W2 = (const float*)d_in[2];
    float* out = (float*)d_out;

    char* ws = (char*)d_ws;
    size_t off = 0;
    auto alloc = [&](size_t bytes) -> void* {
        void* p = ws + off;
        off += (bytes + 255) & ~(size_t)255;
        return p;
    };
    u16*   Xb  = (u16*)  alloc((size_t)T * B * IN * 2);     // [T,B,IN] bf16
    u16*   W1q = (u16*)  alloc((size_t)HID * IN * 2);       // [HID,IN] bf16
    u16*   W2q = (u16*)  alloc((size_t)OUT * HID * 2);      // [OUT,HID] bf16
    float* H   = (float*)alloc((size_t)T * B * HID * 4);    // [T*B, HID] f32
    u16*   S1  = (u16*)  alloc((size_t)T * B * HID * 2);    // [T,B,HID] bf16 (shifted)
    float* O   = (float*)alloc((size_t)T * B * OUT * 4);    // [T*B, OUT] f32
    float* S2  = (float*)alloc((size_t)T * B * OUT * 4);    // [T,B,OUT] f32 (shifted)

    dim3 blk(256);
    transpose_x<<<dim3(T / 32, IN / 32, B), blk, 0, stream>>>(spikes, Xb, B, IN, T);
    quant_w<<<dim3((HID * IN + 255) / 256), blk, 0, stream>>>(W1, W1q, HID * IN);
    quant_w<<<dim3((OUT * HID + 255) / 256), blk, 0, stream>>>(W2, W2q, OUT * HID);
    gemm_bt<<<dim3(HID / 128, (T * B) / 128), blk, 0, stream>>>(Xb, W1q, H, T * B, HID, IN);
    scan1<<<dim3(B * HID / 256), blk, 0, stream>>>(H, S1, B * HID, T);
    gemm_bt<<<dim3(OUT / 128, (T * B) / 128), blk, 0, stream>>>(S1, W2q, O, T * B, OUT, HID);
    scan2<<<dim3(B * OUT / 256), blk, 0, stream>>>(O, S2, B * OUT, T);
    transpose_out<<<dim3(T / 32, OUT / 32, B), blk, 0, stream>>>(S2, out, B, OUT, T);
}

// Round 2
// 152.171 us; speedup vs baseline: 1.7693x; 1.7693x over previous
//
#include <hip/hip_runtime.h>
#include <hip/hip_bf16.h>

typedef unsigned short u16;
typedef __attribute__((ext_vector_type(4))) float f32x4;
typedef __bf16 bf16x8 __attribute__((ext_vector_type(8)));

#define AS1 __attribute__((address_space(1)))
#define AS3 __attribute__((address_space(3)))

__device__ __forceinline__ void gload_lds16(const void* g, void* l) {
    __builtin_amdgcn_global_load_lds((const AS1 void*)g, (AS3 void*)l, 16, 0, 0);
}

// ---------------- transpose [B, IN, T] f32 -> [T, B, IN] bf16 ----------------
__global__ void transpose_x(const float* __restrict__ X, u16* __restrict__ Xb,
                            int B, int IN, int T) {
    __shared__ float tile[32][33];
    const int t0 = blockIdx.x * 32, i0 = blockIdx.y * 32, b = blockIdx.z;
    const int tx = threadIdx.x & 31, ty = threadIdx.x >> 5;
    const float* src = X + (size_t)b * IN * T;
#pragma unroll
    for (int r = 0; r < 4; ++r) {
        int i = ty + r * 8;
        tile[i][tx] = src[(size_t)(i0 + i) * T + t0 + tx];
    }
    __syncthreads();
#pragma unroll
    for (int r = 0; r < 4; ++r) {
        int tl = ty + r * 8;
        float v = tile[tx][tl];
        Xb[(size_t)(t0 + tl) * ((size_t)B * IN) + (size_t)b * IN + i0 + tx] =
            (u16)(__float_as_uint(v) >> 16);   // 0.0/1.0 exact in bf16
    }
}

// ---------------- quantize: round(w/2)*2 (half-to-even), to bf16 -------------
__global__ void quant_w(const float* __restrict__ W, u16* __restrict__ Wq, int n) {
    int i = blockIdx.x * 256 + threadIdx.x;
    if (i < n) {
        float q = rintf(W[i] * 0.5f) * 2.0f;   // small even integer: bf16-exact
        Wq[i] = (u16)(__float_as_uint(q) >> 16);
    }
}

// ---------------- GEMM: C[M,N] f32 = A[M,K]bf16 * Bt[N,K]bf16 ----------------
__global__ __launch_bounds__(256, 2) void gemm_bt(
        const u16* __restrict__ A, const u16* __restrict__ Bt,
        float* __restrict__ C, int M, int N, int K, int nbx) {
    __shared__ __align__(16) u16 lA[128 * 64];
    __shared__ __align__(16) u16 lB[128 * 64];
    const int nwg = gridDim.x;
    const int cpx = nwg >> 3;                     // nwg % 8 == 0 by construction
    const int wg  = (blockIdx.x & 7) * cpx + (blockIdx.x >> 3);
    const int bx = wg % nbx, by = wg / nbx;

    const int tid  = threadIdx.x;
    const int lane = tid & 63;
    const int wave = tid >> 6;
    const int wm = wave >> 1, wn = wave & 1;
    const int m0 = by * 128;
    const int n0 = bx * 128;
    const int l15 = lane & 15;
    const int l4  = lane >> 4;

    f32x4 acc[4][4] = {};
    const int flatT = tid * 8;

    for (int k0 = 0; k0 < K; k0 += 64) {
        __syncthreads();
#pragma unroll
        for (int q = 0; q < 4; ++q) {
            int fl = q * 2048 + flatT;
            int r = fl >> 6, c = fl & 63;
            gload_lds16(A + (size_t)(m0 + r) * K + k0 + c, &lA[fl]);
        }
#pragma unroll
        for (int q = 0; q < 4; ++q) {
            int fl = q * 2048 + flatT;
            int r = fl >> 6, c = fl & 63;
            gload_lds16(Bt + (size_t)(n0 + r) * K + k0 + c, &lB[fl]);
        }
        __syncthreads();
#pragma unroll
        for (int kk = 0; kk < 2; ++kk) {
            bf16x8 af[4], bf[4];
#pragma unroll
            for (int mf = 0; mf < 4; ++mf)
                af[mf] = *(const bf16x8*)&lA[(wm * 64 + mf * 16 + l15) * 64 + kk * 32 + l4 * 8];
#pragma unroll
            for (int nf = 0; nf < 4; ++nf)
                bf[nf] = *(const bf16x8*)&lB[(wn * 64 + nf * 16 + l15) * 64 + kk * 32 + l4 * 8];
#pragma unroll
            for (int mf = 0; mf < 4; ++mf)
#pragma unroll
                for (int nf = 0; nf < 4; ++nf)
                    acc[mf][nf] = __builtin_amdgcn_mfma_f32_16x16x32_bf16(
                        af[mf], bf[nf], acc[mf][nf], 0, 0, 0);
        }
    }
#pragma unroll
    for (int mf = 0; mf < 4; ++mf)
#pragma unroll
        for (int nf = 0; nf < 4; ++nf) {
            int col = n0 + wn * 64 + nf * 16 + l15;
#pragma unroll
            for (int j = 0; j < 4; ++j) {
                int row = m0 + wm * 64 + mf * 16 + l4 * 4 + j;
                C[(size_t)row * N + col] = acc[mf][nf][j];
            }
        }
}

// ---------------- Loihi neuron scan (pre-shifted output), 32-deep dbuf -------
// OUT_BF16: write bf16 1.0 (0x3F80) / 0; else f32 spike values.
template <bool OUT_BF16, typename OutT>
__global__ void scan_loihi(const float* __restrict__ Hin, OutT* __restrict__ S,
                           int BH) {
    const int idx = blockIdx.x * 256 + threadIdx.x;
    const float* p = Hin + idx;
    OutT* q = S + idx;
    if (OUT_BF16) q[0] = (OutT)0; else ((float*)q)[0] = 0.f;

    float a[32], b[32];
#pragma unroll
    for (int u = 0; u < 32; ++u) a[u] = p[(size_t)u * BH];
    float I = 0.f, V = 0.f;

    auto emit = [&](float s, int tt) {
        if (OUT_BF16) q[(size_t)tt * BH] = (OutT)((s > 0.f) ? 0x3F80 : 0);
        else ((float*)q)[(size_t)tt * BH] = s;
    };

    for (int t = 0; t < 256; t += 64) {
#pragma unroll
        for (int u = 0; u < 32; ++u) b[u] = p[(size_t)(t + 32 + u) * BH];
#pragma unroll
        for (int u = 0; u < 32; ++u) {
            I = floorf(I * 0.75f) + 64.f * a[u];
            V = floorf(V * 0.96875f) + I;
            float s = (V >= 5120.f) ? 1.f : 0.f;
            V *= (1.f - s);
            emit(s, t + u + 1);                    // tt <= 224
        }
        if (t + 64 < 256) {
#pragma unroll
            for (int u = 0; u < 32; ++u) a[u] = p[(size_t)(t + 64 + u) * BH];
        }
#pragma unroll
        for (int u = 0; u < 32; ++u) {
            I = floorf(I * 0.75f) + 64.f * b[u];
            V = floorf(V * 0.96875f) + I;
            float s = (V >= 5120.f) ? 1.f : 0.f;
            V *= (1.f - s);
            int tt = t + 32 + u + 1;
            if (tt < 256) emit(s, tt);
        }
    }
}

// ---------------- transpose [T, B, OUT] -> out [B, OUT, T] -------------------
__global__ void transpose_out(const float* __restrict__ S, float* __restrict__ out,
                              int B, int OUT, int T) {
    __shared__ float tile[32][33];
    const int t0 = blockIdx.x * 32, o0 = blockIdx.y * 32, b = blockIdx.z;
    const int tx = threadIdx.x & 31, ty = threadIdx.x >> 5;
#pragma unroll
    for (int r = 0; r < 4; ++r) {
        int t = ty + r * 8;
        tile[t][tx] = S[(size_t)(t0 + t) * B * OUT + (size_t)b * OUT + o0 + tx];
    }
    __syncthreads();
#pragma unroll
    for (int r = 0; r < 4; ++r) {
        int o = ty + r * 8;
        out[(size_t)b * OUT * T + (size_t)(o0 + o) * T + t0 + tx] = tile[tx][o];
    }
}

extern "C" void kernel_launch(void* const* d_in, const int* in_sizes, int n_in,
                              void* d_out, int out_size, void* d_ws, size_t ws_size,
                              hipStream_t stream) {
    const int B = 32, IN = 1024, HID = 2048, OUT = 512, T = 256;
    const float* spikes = (const float*)d_in[0];
    const float* W1 = (const float*)d_in[1];
    const float* W2 = (const float*)d_in[2];
    float* out = (float*)d_out;

    char* ws = (char*)d_ws;
    size_t off = 0;
    auto alloc = [&](size_t bytes) -> void* {
        void* p = ws + off;
        off += (bytes + 255) & ~(size_t)255;
        return p;
    };
    u16*   Xb  = (u16*)  alloc((size_t)T * B * IN * 2);
    u16*   W1q = (u16*)  alloc((size_t)HID * IN * 2);
    u16*   W2q = (u16*)  alloc((size_t)OUT * HID * 2);
    float* H   = (float*)alloc((size_t)T * B * HID * 4);
    u16*   S1  = (u16*)  alloc((size_t)T * B * HID * 2);
    float* O   = (float*)alloc((size_t)T * B * OUT * 4);
    float* S2  = (float*)alloc((size_t)T * B * OUT * 4);

    dim3 blk(256);
    transpose_x<<<dim3(T / 32, IN / 32, B), blk, 0, stream>>>(spikes, Xb, B, IN, T);
    quant_w<<<dim3((HID * IN + 255) / 256), blk, 0, stream>>>(W1, W1q, HID * IN);
    quant_w<<<dim3((OUT * HID + 255) / 256), blk, 0, stream>>>(W2, W2q, OUT * HID);

    {   // GEMM1: 16 x 64 = 1024 wgs (divisible by 8 -> simple bijective swizzle)
        int nbx = HID / 128, nby = (T * B) / 128;
        gemm_bt<<<dim3(nbx * nby), blk, 0, stream>>>(Xb, W1q, H, T * B, HID, IN, nbx);
    }
    scan_loihi<true, u16><<<dim3(B * HID / 256), blk, 0, stream>>>(H, S1, B * HID);
    {   // GEMM2: 4 x 64 = 256 wgs
        int nbx = OUT / 128, nby = (T * B) / 128;
        gemm_bt<<<dim3(nbx * nby), blk, 0, stream>>>(S1, W2q, O, T * B, OUT, HID, nbx);
    }
    scan_loihi<false, float><<<dim3(B * OUT / 256), blk, 0, stream>>>(O, S2, B * OUT);
    transpose_out<<<dim3(T / 32, OUT / 32, B), blk, 0, stream>>>(S2, out, B, OUT, T);
}

// Round 3
// 98.442 us; speedup vs baseline: 2.7351x; 1.5458x over previous
//
#include <hip/hip_runtime.h>
#include <hip/hip_bf16.h>

typedef unsigned short u16;
typedef unsigned char u8;
typedef signed char i8;
typedef __attribute__((ext_vector_type(4))) int i32x4;

#define AS1 __attribute__((address_space(1)))
#define AS3 __attribute__((address_space(3)))

__device__ __forceinline__ void gload_lds16(const void* g, void* l) {
    __builtin_amdgcn_global_load_lds((const AS1 void*)g, (AS3 void*)l, 16, 0, 0);
}

// ------------- transpose [B, IN, T] f32 -> [T, B, IN] i8 (0/1) ---------------
__global__ void transpose_x2(const float* __restrict__ X, i8* __restrict__ Xb,
                             int B, int IN, int T) {
    __shared__ float tile[128][33];          // [i_loc][t_loc]
    const int t0 = blockIdx.x * 32, i0 = blockIdx.y * 128, b = blockIdx.z;
    const int tx = threadIdx.x & 31, ty = threadIdx.x >> 5;
    const float* src = X + (size_t)b * IN * T;
#pragma unroll
    for (int r = 0; r < 16; ++r) {
        int i = ty + r * 8;
        tile[i][tx] = src[(size_t)(i0 + i) * T + t0 + tx];
    }
    __syncthreads();
    const int cx = threadIdx.x & 31;         // which 4-byte chunk of 128 i's
    const int tl0 = threadIdx.x >> 5;
#pragma unroll
    for (int r = 0; r < 4; ++r) {
        int tl = tl0 + r * 8;                // t within tile
        uchar4 pk;
        pk.x = (tile[cx * 4 + 0][tl] != 0.f) ? 1 : 0;
        pk.y = (tile[cx * 4 + 1][tl] != 0.f) ? 1 : 0;
        pk.z = (tile[cx * 4 + 2][tl] != 0.f) ? 1 : 0;
        pk.w = (tile[cx * 4 + 3][tl] != 0.f) ? 1 : 0;
        *(uchar4*)&Xb[(size_t)(t0 + tl) * B * IN + (size_t)b * IN + i0 + cx * 4] = pk;
    }
}

// ------------- quantize: w -> i8( round_half_even(w/2) ), exact --------------
__global__ void quant_w(const float* __restrict__ W, i8* __restrict__ Wq, int n) {
    int i = blockIdx.x * 256 + threadIdx.x;
    if (i < n) Wq[i] = (i8)(int)rintf(W[i] * 0.5f);
}

// ------------- i8 GEMM: C[M,N] = 2 * (A[M,K]i8 . Bt[N,K]i8^T) ----------------
template <int WRITE_I16>
__global__ __launch_bounds__(256, 2) void gemm_i8(
        const i8* __restrict__ A, const i8* __restrict__ Bt,
        void* __restrict__ Cv, int M, int N, int K, int nbx) {
    __shared__ __align__(16) i8 lA[128 * 128];
    __shared__ __align__(16) i8 lB[128 * 128];
    const int nwg = gridDim.x;
    const int cpx = nwg >> 3;                       // nwg % 8 == 0 by launch
    const int wg  = (blockIdx.x & 7) * cpx + (blockIdx.x >> 3);
    const int bx = wg % nbx, by = wg / nbx;

    const int tid  = threadIdx.x;
    const int lane = tid & 63;
    const int wave = tid >> 6;
    const int wm = wave >> 1, wn = wave & 1;
    const int m0 = by * 128;
    const int n0 = bx * 128;
    const int l15 = lane & 15;
    const int l4  = lane >> 4;

    i32x4 acc[4][4] = {};
    const int flatT = tid * 16;                     // 16 B per lane per issue

    for (int k0 = 0; k0 < K; k0 += 128) {
        __syncthreads();
#pragma unroll
        for (int q = 0; q < 4; ++q) {
            int fl = q * 4096 + flatT;
            int r = fl >> 7, c = fl & 127;
            gload_lds16(A + (size_t)(m0 + r) * K + k0 + c, &lA[fl]);
        }
#pragma unroll
        for (int q = 0; q < 4; ++q) {
            int fl = q * 4096 + flatT;
            int r = fl >> 7, c = fl & 127;
            gload_lds16(Bt + (size_t)(n0 + r) * K + k0 + c, &lB[fl]);
        }
        __syncthreads();
#pragma unroll
        for (int kk = 0; kk < 2; ++kk) {
            i32x4 af[4], bf[4];
#pragma unroll
            for (int mf = 0; mf < 4; ++mf)
                af[mf] = *(const i32x4*)&lA[(wm * 64 + mf * 16 + l15) * 128 + kk * 64 + l4 * 16];
#pragma unroll
            for (int nf = 0; nf < 4; ++nf)
                bf[nf] = *(const i32x4*)&lB[(wn * 64 + nf * 16 + l15) * 128 + kk * 64 + l4 * 16];
#pragma unroll
            for (int mf = 0; mf < 4; ++mf)
#pragma unroll
                for (int nf = 0; nf < 4; ++nf)
                    acc[mf][nf] = __builtin_amdgcn_mfma_i32_16x16x64_i8(
                        af[mf], bf[nf], acc[mf][nf], 0, 0, 0);
        }
    }
#pragma unroll
    for (int mf = 0; mf < 4; ++mf)
#pragma unroll
        for (int nf = 0; nf < 4; ++nf) {
            int col = n0 + wn * 64 + nf * 16 + l15;
#pragma unroll
            for (int j = 0; j < 4; ++j) {
                int row = m0 + wm * 64 + mf * 16 + l4 * 4 + j;
                int v2 = acc[mf][nf][j] * 2;        // undo w/2 scaling, exact
                if (WRITE_I16) ((short*)Cv)[(size_t)row * N + col] = (short)v2;
                else           ((float*)Cv)[(size_t)row * N + col] = (float)v2;
            }
        }
}

// ------------- Loihi neuron scan (pre-shifted output), 32-deep dbuf ----------
template <bool IN_I16, bool OUT_I8>
__global__ void scan_loihi(const void* __restrict__ Hin, void* __restrict__ Sout,
                           int BH) {
    const int idx = blockIdx.x * 256 + threadIdx.x;
    const short* ps = (const short*)Hin + idx;
    const float* pf = (const float*)Hin + idx;
    i8*    qs = (i8*)Sout + idx;
    float* qf = (float*)Sout + idx;
    if (OUT_I8) qs[0] = 0; else qf[0] = 0.f;       // t=0 row (delay shift)

    float a[32], b[32];
#pragma unroll
    for (int u = 0; u < 32; ++u)
        a[u] = IN_I16 ? (float)ps[(size_t)u * BH] : pf[(size_t)u * BH];
    float I = 0.f, V = 0.f;

    for (int t = 0; t < 256; t += 64) {
#pragma unroll
        for (int u = 0; u < 32; ++u)
            b[u] = IN_I16 ? (float)ps[(size_t)(t + 32 + u) * BH]
                          : pf[(size_t)(t + 32 + u) * BH];
#pragma unroll
        for (int u = 0; u < 32; ++u) {
            I = floorf(I * 0.75f) + 64.f * a[u];
            V = floorf(V * 0.96875f) + I;
            float s = (V >= 5120.f) ? 1.f : 0.f;
            V *= (1.f - s);
            int tt = t + u + 1;                     // <= 224, in range
            if (OUT_I8) qs[(size_t)tt * BH] = (i8)(s > 0.f ? 1 : 0);
            else        qf[(size_t)tt * BH] = s;
        }
        if (t + 64 < 256) {
#pragma unroll
            for (int u = 0; u < 32; ++u)
                a[u] = IN_I16 ? (float)ps[(size_t)(t + 64 + u) * BH]
                              : pf[(size_t)(t + 64 + u) * BH];
        }
#pragma unroll
        for (int u = 0; u < 32; ++u) {
            I = floorf(I * 0.75f) + 64.f * b[u];
            V = floorf(V * 0.96875f) + I;
            float s = (V >= 5120.f) ? 1.f : 0.f;
            V *= (1.f - s);
            int tt = t + 32 + u + 1;
            if (tt < 256) {
                if (OUT_I8) qs[(size_t)tt * BH] = (i8)(s > 0.f ? 1 : 0);
                else        qf[(size_t)tt * BH] = s;
            }
        }
    }
}

// ------------- transpose [T, B, OUT] f32 -> out [B, OUT, T] f32 --------------
__global__ void transpose_out(const float* __restrict__ S, float* __restrict__ out,
                              int B, int OUT, int T) {
    __shared__ float tile[32][33];
    const int t0 = blockIdx.x * 32, o0 = blockIdx.y * 32, b = blockIdx.z;
    const int tx = threadIdx.x & 31, ty = threadIdx.x >> 5;
#pragma unroll
    for (int r = 0; r < 4; ++r) {
        int t = ty + r * 8;
        tile[t][tx] = S[(size_t)(t0 + t) * B * OUT + (size_t)b * OUT + o0 + tx];
    }
    __syncthreads();
#pragma unroll
    for (int r = 0; r < 4; ++r) {
        int o = ty + r * 8;
        out[(size_t)b * OUT * T + (size_t)(o0 + o) * T + t0 + tx] = tile[tx][o];
    }
}

extern "C" void kernel_launch(void* const* d_in, const int* in_sizes, int n_in,
                              void* d_out, int out_size, void* d_ws, size_t ws_size,
                              hipStream_t stream) {
    const int B = 32, IN = 1024, HID = 2048, OUT = 512, T = 256;
    const float* spikes = (const float*)d_in[0];
    const float* W1 = (const float*)d_in[1];
    const float* W2 = (const float*)d_in[2];
    float* out = (float*)d_out;

    char* ws = (char*)d_ws;
    size_t off = 0;
    auto alloc = [&](size_t bytes) -> void* {
        void* p = ws + off;
        off += (bytes + 255) & ~(size_t)255;
        return p;
    };
    i8*    Xb  = (i8*)   alloc((size_t)T * B * IN);         // [T,B,IN] i8 0/1
    i8*    W1q = (i8*)   alloc((size_t)HID * IN);           // [HID,IN] i8 = w/2
    i8*    W2q = (i8*)   alloc((size_t)OUT * HID);          // [OUT,HID] i8 = w/2
    short* H   = (short*)alloc((size_t)T * B * HID * 2);    // [T,B,HID] i16 exact
    i8*    S1  = (i8*)   alloc((size_t)T * B * HID);        // [T,B,HID] i8 spikes (shifted)
    float* O   = (float*)alloc((size_t)T * B * OUT * 4);    // [T,B,OUT] f32 exact
    float* S2  = (float*)alloc((size_t)T * B * OUT * 4);    // [T,B,OUT] f32 (shifted)

    dim3 blk(256);
    transpose_x2<<<dim3(T / 32, IN / 128, B), blk, 0, stream>>>(spikes, Xb, B, IN, T);
    quant_w<<<dim3((HID * IN + 255) / 256), blk, 0, stream>>>(W1, W1q, HID * IN);
    quant_w<<<dim3((OUT * HID + 255) / 256), blk, 0, stream>>>(W2, W2q, OUT * HID);

    {   // GEMM1: [8192,1024]i8 x [2048,1024]i8^T -> H i16 ; 16x64=1024 wgs
        int nbx = HID / 128, nby = (T * B) / 128;
        gemm_i8<1><<<dim3(nbx * nby), blk, 0, stream>>>(Xb, W1q, H, T * B, HID, IN, nbx);
    }
    scan_loihi<true, true><<<dim3(B * HID / 256), blk, 0, stream>>>(H, S1, B * HID);
    {   // GEMM2: [8192,2048]i8 x [512,2048]i8^T -> O f32 ; 4x64=256 wgs
        int nbx = OUT / 128, nby = (T * B) / 128;
        gemm_i8<0><<<dim3(nbx * nby), blk, 0, stream>>>(S1, W2q, O, T * B, OUT, HID, nbx);
    }
    scan_loihi<false, false><<<dim3(B * OUT / 256), blk, 0, stream>>>(O, S2, B * OUT);
    transpose_out<<<dim3(T / 32, OUT / 32, B), blk, 0, stream>>>(S2, out, B, OUT, T);
}